// Round 1
// baseline (149.560 us; speedup 1.0000x reference)
//
#include <hip/hip_runtime.h>

// Problem constants (match reference)
#define BB 128
#define SS 8192
#define VV 128000

// Output element offsets (flat float32 view of d_out, tuple return order)
#define OFF_TOK 0
#define OFF_LTI (OFF_TOK + BB)
#define OFF_MASK (OFF_LTI + BB)            // 256
#define OFF_GEN (OFF_MASK + BB * SS)       // 1048832
#define OFF_STR (OFF_GEN + BB * SS)        // 2097408
#define OFF_GI  (OFF_STR + BB * SS)        // 3145984
#define OFF_CNT (OFF_GI + BB)              // 3146112

// Native clang vectors — required by __builtin_nontemporal_store
typedef float f32x4 __attribute__((ext_vector_type(4)));
typedef int   i32x4 __attribute__((ext_vector_type(4)));

// Geometry: one block = 2048 float4 chunks = 32 KiB (elements).
//  - S-regions: 2048 chunks == exactly one batch row (8192 elems) -> b is
//    block-uniform -> lti/gi/tokens hoist to one scalar load per block.
//  - count region: 4,096,000 chunks / 2048 = 2000 blocks exactly.
//  - every region boundary is a multiple of 2048 chunks -> block-uniform branches.
#define NB_S   128                     // blocks per S-region: 128*8192/4 / 2048
#define NB_CNT 2000                    // 128*128000/4 / 2048
#define NB_TOTAL (3 * NB_S + NB_CNT + 1)   // 2385 (last block: tiny outputs)

__global__ void __launch_bounds__(256)
k_fused(const int* __restrict__ tokens,
        const int* __restrict__ lti_in,
        const float* __restrict__ mask_in,
        const int* __restrict__ gen_in,
        const int* __restrict__ str_in,
        const int* __restrict__ gi_in,
        const int* __restrict__ cnt_in,
        float* __restrict__ out)
{
    const int bid = blockIdx.x;
    const int tid = threadIdx.x;

    if (bid < 3 * NB_S) {
        // ---- attention_mask / generated_tokens / generated_tokens_streaming ----
        const int region = bid >> 7;       // 0=mask, 1=gen, 2=str (block-uniform)
        const int b      = bid & 127;      // this block owns batch row b entirely

        if (region == 0) {
            const int lti_new = min(lti_in[b] + 1, SS - 1);   // one scalar load/block
            #pragma unroll
            for (int p = 0; p < 8; ++p) {
                const int    cw = p * 256 + tid;              // chunk within row
                const int    s0 = cw << 2;                    // first s of chunk
                const size_t e  = (((size_t)b << 11) + cw) << 2;
                f32x4 m = *(const f32x4*)(mask_in + e);       // plain cached load
                if ((unsigned)(lti_new - s0) < 4u)
                    m[lti_new - s0] = 1.0f;
                __builtin_nontemporal_store(m, (f32x4*)(out + OFF_MASK + e));
            }
        } else {
            const int*  src = (region == 1) ? gen_in : str_in;
            float*      dst = out + ((region == 1) ? OFF_GEN : OFF_STR);
            const int   gi_old = gi_in[b];                    // scatter at PRE-increment idx
            const float tokf   = (float)tokens[b];
            #pragma unroll
            for (int p = 0; p < 8; ++p) {
                const int    cw = p * 256 + tid;
                const int    s0 = cw << 2;
                const size_t e  = (((size_t)b << 11) + cw) << 2;
                i32x4 g = *(const i32x4*)(src + e);           // plain cached load
                f32x4 go = { (float)g[0], (float)g[1], (float)g[2], (float)g[3] };
                if ((unsigned)(gi_old - s0) < 4u)
                    go[gi_old - s0] = tokf;
                __builtin_nontemporal_store(go, (f32x4*)(dst + e));
            }
        }
    } else if (bid < 3 * NB_S + NB_CNT) {
        // ---- token_count: copy int->float, +1 at tokens[b] per row (no atomics) ----
        const int rbid = bid - 3 * NB_S;
        #pragma unroll
        for (int p = 0; p < 8; ++p) {
            const int    rc = rbid * 2048 + p * 256 + tid;    // chunk in count region
            const int    b  = rc / 32000;                     // 32000 chunks per V-row
            const int    v0 = (rc - b * 32000) << 2;
            const size_t e  = (size_t)rc << 2;
            i32x4 cc = *(const i32x4*)(cnt_in + e);           // plain cached load
            f32x4 co = { (float)cc[0], (float)cc[1], (float)cc[2], (float)cc[3] };
            const int tok = tokens[b];                        // L1-hit broadcast
            if ((unsigned)(tok - v0) < 4u)
                co[tok - v0] += 1.0f;
            __builtin_nontemporal_store(co, (f32x4*)(out + OFF_CNT + e));
        }
    } else {
        // ---- tiny (B,) outputs: tokens, lti+1 clamped, gi+1 clamped ----
        if (tid < BB) {
            out[OFF_TOK + tid] = (float)tokens[tid];
            out[OFF_LTI + tid] = (float)min(lti_in[tid] + 1, SS - 1);
            out[OFF_GI  + tid] = (float)min(gi_in[tid] + 1, SS - 1);
        }
    }
}

extern "C" void kernel_launch(void* const* d_in, const int* in_sizes, int n_in,
                              void* d_out, int out_size, void* d_ws, size_t ws_size,
                              hipStream_t stream) {
    const int*   tokens = (const int*)  d_in[0];
    const int*   lti    = (const int*)  d_in[1];
    const float* mask   = (const float*)d_in[2];
    const int*   gen    = (const int*)  d_in[3];
    const int*   strm   = (const int*)  d_in[4];
    const int*   gi     = (const int*)  d_in[5];
    const int*   cnt    = (const int*)  d_in[6];
    float* out = (float*)d_out;

    k_fused<<<dim3(NB_TOTAL), dim3(256), 0, stream>>>(
        tokens, lti, mask, gen, strm, gi, cnt, out);
}

// Round 2
// 146.366 us; speedup vs baseline: 1.0218x; 1.0218x over previous
//
#include <hip/hip_runtime.h>

// Problem constants (match reference)
#define BB 128
#define SS 8192
#define VV 128000

// Output element offsets (flat float32 view of d_out, tuple return order)
#define OFF_TOK 0
#define OFF_LTI (OFF_TOK + BB)
#define OFF_MASK (OFF_LTI + BB)            // 256
#define OFF_GEN (OFF_MASK + BB * SS)       // 1048832
#define OFF_STR (OFF_GEN + BB * SS)        // 2097408
#define OFF_GI  (OFF_STR + BB * SS)        // 3145984
#define OFF_CNT (OFF_GI + BB)              // 3146112

// Native clang vectors — required by __builtin_nontemporal_{load,store}
typedef float f32x4 __attribute__((ext_vector_type(4)));
typedef int   i32x4 __attribute__((ext_vector_type(4)));

// Round-0 proven geometry: one block = 1024 float4 chunks (256 thr x 4 chunks).
#define NB_S   256     // blocks per S-region: 128*8192/4096
#define NB_CNT 4000    // blocks for count region: 128*128000/4096
#define NB_TOTAL (3 * NB_S + NB_CNT + 1)   // 4769

__global__ void __launch_bounds__(256)
k_fused(const int* __restrict__ tokens,
        const int* __restrict__ lti_in,
        const float* __restrict__ mask_in,
        const int* __restrict__ gen_in,
        const int* __restrict__ str_in,
        const int* __restrict__ gi_in,
        const int* __restrict__ cnt_in,
        float* __restrict__ out)
{
    const int bid = blockIdx.x;
    const int tid = threadIdx.x;

    if (bid < 3 * NB_S) {
        // ---- attention_mask / generated_tokens / generated_tokens_streaming ----
        const int region = bid >> 8;       // 0=mask, 1=gen, 2=str (block-uniform)
        const int rbid   = bid & 255;
        const int b      = rbid >> 1;      // 2 blocks per S-row -> block-uniform

        if (region == 0) {
            // ONE scalar load per block (was: per-chunk broadcast load)
            const int lti_new = min(lti_in[b] + 1, SS - 1);
            #pragma unroll
            for (int j = 0; j < 4; ++j) {
                const int    c  = rbid * 1024 + j * 256 + tid;  // float4 chunk in region
                const int    s0 = (c & 2047) << 2;              // first s covered by chunk
                const size_t e  = (size_t)c << 2;
                f32x4 m = __builtin_nontemporal_load((const f32x4*)(mask_in + e));
                if ((unsigned)(lti_new - s0) < 4u)
                    m[lti_new - s0] = 1.0f;
                __builtin_nontemporal_store(m, (f32x4*)(out + OFF_MASK + e));
            }
        } else {
            const int*  src  = (region == 1) ? gen_in : str_in;
            float*      dstp = out + ((region == 1) ? OFF_GEN : OFF_STR);
            // ONE pair of scalar loads per block (was: per-chunk broadcast loads)
            const int   gi_old = gi_in[b];              // scatter at PRE-increment idx
            const float tokf   = (float)tokens[b];
            #pragma unroll
            for (int j = 0; j < 4; ++j) {
                const int    c  = rbid * 1024 + j * 256 + tid;
                const int    s0 = (c & 2047) << 2;
                const size_t e  = (size_t)c << 2;
                i32x4 g = __builtin_nontemporal_load((const i32x4*)(src + e));
                f32x4 go = { (float)g[0], (float)g[1], (float)g[2], (float)g[3] };
                if ((unsigned)(gi_old - s0) < 4u)
                    go[gi_old - s0] = tokf;
                __builtin_nontemporal_store(go, (f32x4*)(dstp + e));
            }
        }
    } else if (bid < 3 * NB_S + NB_CNT) {
        // ---- token_count: copy int->float, +1 at tokens[b] per row (no atomics) ----
        // A 1024-chunk block spans at most 2 vocab rows (32000 chunks/row).
        // Preload the (at most) two tokens -> zero per-chunk VMEM broadcasts,
        // zero per-chunk divisions.
        const int rbid  = bid - 3 * NB_S;
        const int c0    = rbid * 1024;              // first chunk of this block
        const int b0    = c0 / 32000;               // block-uniform
        const int base0 = b0 * 32000;
        const int cSw   = base0 + 32000;            // first chunk of row b0+1
        const int tok0  = tokens[b0];
        const int b1    = (c0 + 1023 >= cSw) ? (b0 + 1) : b0;  // never exceeds 127
        const int tok1  = tokens[b1];
        #pragma unroll
        for (int j = 0; j < 4; ++j) {
            const int    c    = c0 + j * 256 + tid;
            const bool   lo   = (c < cSw);
            const int    tok  = lo ? tok0 : tok1;
            const int    base = lo ? base0 : cSw;
            const int    v0   = (c - base) << 2;    // first vocab idx of chunk
            const size_t e    = (size_t)c << 2;
            i32x4 cc = __builtin_nontemporal_load((const i32x4*)(cnt_in + e));
            f32x4 co = { (float)cc[0], (float)cc[1], (float)cc[2], (float)cc[3] };
            if ((unsigned)(tok - v0) < 4u)
                co[tok - v0] += 1.0f;
            __builtin_nontemporal_store(co, (f32x4*)(out + OFF_CNT + e));
        }
    } else {
        // ---- tiny (B,) outputs: tokens, lti+1 clamped, gi+1 clamped ----
        if (tid < BB) {
            out[OFF_TOK + tid] = (float)tokens[tid];
            out[OFF_LTI + tid] = (float)min(lti_in[tid] + 1, SS - 1);
            out[OFF_GI  + tid] = (float)min(gi_in[tid] + 1, SS - 1);
        }
    }
}

extern "C" void kernel_launch(void* const* d_in, const int* in_sizes, int n_in,
                              void* d_out, int out_size, void* d_ws, size_t ws_size,
                              hipStream_t stream) {
    const int*   tokens = (const int*)  d_in[0];
    const int*   lti    = (const int*)  d_in[1];
    const float* mask   = (const float*)d_in[2];
    const int*   gen    = (const int*)  d_in[3];
    const int*   strm   = (const int*)  d_in[4];
    const int*   gi     = (const int*)  d_in[5];
    const int*   cnt    = (const int*)  d_in[6];
    float* out = (float*)d_out;

    k_fused<<<dim3(NB_TOTAL), dim3(256), 0, stream>>>(
        tokens, lti, mask, gen, strm, gi, cnt, out);
}

// Round 3
// 137.928 us; speedup vs baseline: 1.0843x; 1.0612x over previous
//
#include <hip/hip_runtime.h>

// Problem constants (match reference)
#define BB 128
#define SS 8192
#define VV 128000

// Output element offsets (flat float32 view of d_out, tuple return order)
#define OFF_TOK 0
#define OFF_LTI (OFF_TOK + BB)
#define OFF_MASK (OFF_LTI + BB)            // 256
#define OFF_GEN (OFF_MASK + BB * SS)       // 1048832
#define OFF_STR (OFF_GEN + BB * SS)        // 2097408
#define OFF_GI  (OFF_STR + BB * SS)        // 3145984
#define OFF_CNT (OFF_GI + BB)              // 3146112

// Native clang vectors
typedef float f32x4 __attribute__((ext_vector_type(4)));
typedef int   i32x4 __attribute__((ext_vector_type(4)));

// Round-0 proven geometry: one block = 1024 float4 chunks (256 thr x 4 chunks).
#define NB_S   256     // blocks per S-region: 128*8192/4096
#define NB_CNT 4000    // blocks for count region: 128*128000/4096
#define NB_TOTAL (3 * NB_S + NB_CNT + 1)   // 4769

__global__ void __launch_bounds__(256)
k_fused(const int* __restrict__ tokens,
        const int* __restrict__ lti_in,
        const float* __restrict__ mask_in,
        const int* __restrict__ gen_in,
        const int* __restrict__ str_in,
        const int* __restrict__ gi_in,
        const int* __restrict__ cnt_in,
        float* __restrict__ out)
{
    const int bid = blockIdx.x;
    const int tid = threadIdx.x;

    if (bid < 3 * NB_S) {
        // ---- attention_mask / generated_tokens / generated_tokens_streaming ----
        const int region = bid >> 8;       // 0=mask, 1=gen, 2=str (block-uniform)
        const int rbid   = bid & 255;
        const int b      = rbid >> 1;      // 2 blocks per S-row -> block-uniform

        if (region == 0) {
            const int lti_new = min(lti_in[b] + 1, SS - 1);   // one scalar load/block
            #pragma unroll
            for (int j = 0; j < 4; ++j) {
                const int    c  = rbid * 1024 + j * 256 + tid;  // float4 chunk in region
                const int    s0 = (c & 2047) << 2;              // first s covered by chunk
                const size_t e  = (size_t)c << 2;
                f32x4 m = __builtin_nontemporal_load((const f32x4*)(mask_in + e));
                if ((unsigned)(lti_new - s0) < 4u)
                    m[lti_new - s0] = 1.0f;
                *(f32x4*)(out + OFF_MASK + e) = m;              // PLAIN store (was NT)
            }
        } else {
            const int*  src  = (region == 1) ? gen_in : str_in;
            float*      dstp = out + ((region == 1) ? OFF_GEN : OFF_STR);
            const int   gi_old = gi_in[b];              // scatter at PRE-increment idx
            const float tokf   = (float)tokens[b];
            #pragma unroll
            for (int j = 0; j < 4; ++j) {
                const int    c  = rbid * 1024 + j * 256 + tid;
                const int    s0 = (c & 2047) << 2;
                const size_t e  = (size_t)c << 2;
                i32x4 g = __builtin_nontemporal_load((const i32x4*)(src + e));
                f32x4 go = { (float)g[0], (float)g[1], (float)g[2], (float)g[3] };
                if ((unsigned)(gi_old - s0) < 4u)
                    go[gi_old - s0] = tokf;
                *(f32x4*)(dstp + e) = go;                       // PLAIN store (was NT)
            }
        }
    } else if (bid < 3 * NB_S + NB_CNT) {
        // ---- token_count: copy int->float, +1 at tokens[b] per row (no atomics) ----
        const int rbid  = bid - 3 * NB_S;
        const int c0    = rbid * 1024;              // first chunk of this block
        const int b0    = c0 / 32000;               // block-uniform
        const int base0 = b0 * 32000;
        const int cSw   = base0 + 32000;            // first chunk of row b0+1
        const int tok0  = tokens[b0];
        const int b1    = (c0 + 1023 >= cSw) ? (b0 + 1) : b0;  // never exceeds 127
        const int tok1  = tokens[b1];
        #pragma unroll
        for (int j = 0; j < 4; ++j) {
            const int    c    = c0 + j * 256 + tid;
            const bool   lo   = (c < cSw);
            const int    tok  = lo ? tok0 : tok1;
            const int    base = lo ? base0 : cSw;
            const int    v0   = (c - base) << 2;    // first vocab idx of chunk
            const size_t e    = (size_t)c << 2;
            i32x4 cc = __builtin_nontemporal_load((const i32x4*)(cnt_in + e));
            f32x4 co = { (float)cc[0], (float)cc[1], (float)cc[2], (float)cc[3] };
            if ((unsigned)(tok - v0) < 4u)
                co[tok - v0] += 1.0f;
            *(f32x4*)(out + OFF_CNT + e) = co;                  // PLAIN store (was NT)
        }
    } else {
        // ---- tiny (B,) outputs: tokens, lti+1 clamped, gi+1 clamped ----
        if (tid < BB) {
            out[OFF_TOK + tid] = (float)tokens[tid];
            out[OFF_LTI + tid] = (float)min(lti_in[tid] + 1, SS - 1);
            out[OFF_GI  + tid] = (float)min(gi_in[tid] + 1, SS - 1);
        }
    }
}

extern "C" void kernel_launch(void* const* d_in, const int* in_sizes, int n_in,
                              void* d_out, int out_size, void* d_ws, size_t ws_size,
                              hipStream_t stream) {
    const int*   tokens = (const int*)  d_in[0];
    const int*   lti    = (const int*)  d_in[1];
    const float* mask   = (const float*)d_in[2];
    const int*   gen    = (const int*)  d_in[3];
    const int*   strm   = (const int*)  d_in[4];
    const int*   gi     = (const int*)  d_in[5];
    const int*   cnt    = (const int*)  d_in[6];
    float* out = (float*)d_out;

    k_fused<<<dim3(NB_TOTAL), dim3(256), 0, stream>>>(
        tokens, lti, mask, gen, strm, gi, cnt, out);
}